// Round 16
// baseline (54.835 us; speedup 1.0000x reference)
//
#include <hip/hip_runtime.h>
#include <hip/hip_bf16.h>

typedef __bf16 bhalf;
typedef __attribute__((ext_vector_type(8)))  __bf16 bhalf8;
typedef __attribute__((ext_vector_type(4)))  float  f32x4;
typedef __attribute__((ext_vector_type(16))) float  f32x16;
typedef __attribute__((ext_vector_type(4)))  unsigned int u32x4;

#define NB   16
#define SEQ  2048
#define DIN  512
#define DOUT 64
#define NTOK (NB*SEQ)
#define NSPLIT 4
#define KVPER (SEQ/NSPLIT)     // 512 kv per split

// ws layout (Q/K/V fragment-packed per 32-token tile, 4 KB/tile — see R8)
#define WT_BYTES (192*512*2)
#define Q_OFF    ((size_t)WT_BYTES)
#define QKV_BYTES ((size_t)NTOK*DOUT*2)
#define K_OFF    (Q_OFF + QKV_BYTES)
#define VT_OFF   (K_OFF + QKV_BYTES)

__device__ __forceinline__ void gl_lds16(const void* g, void* l) {
  __builtin_amdgcn_global_load_lds(
      (const __attribute__((address_space(1))) void*)g,
      (__attribute__((address_space(3))) void*)l, 16, 0, 0);
}

// ---------------------------------------------------------------------------
__global__ __launch_bounds__(256) void prep_w(const float* __restrict__ wk,
                                              bhalf* __restrict__ wt) {
  int tid  = blockIdx.x*256 + threadIdx.x;
  int slot = tid >> 15;
  int rem  = tid & 32767;
  int k    = rem >> 6;
  int col  = rem & 63;
  float v  = wk[tid];
  if (slot == 0) v *= 0.18033688011112042f;    // (1/8)*log2(e)
  wt[(size_t)(slot*64 + col)*DIN + k] = (bhalf)v;
}

// ---------------------------------------------------------------------------
// QKV projection v6 (R9 verbatim — best measured): 512 threads = 8 waves =
// (4 token-groups) x (2 n-groups); dual-operand LDS staging via
// global_load_lds; fragment-packed outputs.
__global__ __launch_bounds__(512) void proj_qkv(const float* __restrict__ x,
    const bhalf* __restrict__ wt, bhalf* __restrict__ qb,
    bhalf* __restrict__ kb, bhalf* __restrict__ vtb) {
  __shared__ __align__(16) char smem[81920];   // xs[2][16KB] + ws[2][24KB]
  char* const xs  = smem;
  char* const wsl = smem + 32768;

  const int tid  = threadIdx.x;
  const int lane = tid & 63;
  const int wv   = tid >> 6;       // 0..7
  const int tg   = wv & 3;         // token group (16 tokens)
  const int ng   = wv >> 2;        // n group: nt 0..5 / 6..11
  const int r16  = lane & 15;
  const int g    = lane >> 4;
  const int tok0 = blockIdx.x * 64;

  const char* const xg = (const char*)(x + (size_t)tok0 * DIN);
  const char* const wg = (const char*)wt;

  auto stage = [&](int buf, int c) {
#pragma unroll
    for (int i = 0; i < 5; ++i) {
      const int p = wv*5 + i;
      if (p < 24) {
        const int n = p*8 + (lane >> 3);
        const int s = lane & 7;
        gl_lds16(wg + (size_t)n*1024 + c*128 + ((s ^ (n & 7)) << 4),
                 wsl + buf*24576 + p*1024);
      } else {
        const int q = p - 24;
        const int r = q*4 + (lane >> 4);
        const int s = lane & 15;
        gl_lds16(xg + (size_t)r*2048 + c*256 + ((s ^ (r & 7)) << 4),
                 xs + buf*16384 + q*1024);
      }
    }
  };

  f32x4 acc0 = {0.f,0.f,0.f,0.f}, acc1 = acc0, acc2 = acc0,
        acc3 = acc0, acc4 = acc0, acc5 = acc0;

  stage(0, 0);
  __syncthreads();

  const int row = tg*16 + r16;
  const int rx7 = r16 & 7;

  int buf = 0;
  for (int c = 0; c < 8; ++c) {
    if (c < 7) stage(buf ^ 1, c + 1);
    const char* xrow = xs  + buf*16384 + row*256;
    const char* wb   = wsl + buf*24576;
#pragma unroll
    for (int kk = 0; kk < 2; ++kk) {
      const int sa = kk*8 + g*2;
      f32x4 xa = *(const f32x4*)(xrow + (( sa      ^ rx7) << 4));
      f32x4 xc = *(const f32x4*)(xrow + (((sa + 1) ^ rx7) << 4));
      bhalf8 a;
      a[0]=(bhalf)xa[0]; a[1]=(bhalf)xa[1]; a[2]=(bhalf)xa[2]; a[3]=(bhalf)xa[3];
      a[4]=(bhalf)xc[0]; a[5]=(bhalf)xc[1]; a[6]=(bhalf)xc[2]; a[7]=(bhalf)xc[3];
      const int sb = (kk*4 + g) ^ rx7;
      __builtin_amdgcn_s_setprio(1);
#define MF(J, ACC) do {                                                         \
        const int nt_ = ng*6 + (J);                                             \
        const bhalf8 bf_ = *(const bhalf8*)(wb + (nt_*16 + r16)*128 + (sb << 4)); \
        ACC = __builtin_amdgcn_mfma_f32_16x16x32_bf16(a, bf_, ACC, 0, 0, 0);    \
      } while (0)
      MF(0, acc0); MF(1, acc1); MF(2, acc2);
      MF(3, acc3); MF(4, acc4); MF(5, acc5);
#undef MF
      __builtin_amdgcn_s_setprio(0);
    }
    __syncthreads();
    buf ^= 1;
  }

#define STOREJ(J, ACC) do {                                                     \
    const int nt = ng*6 + (J);                                                  \
    if (nt < 8) {                                                               \
      bhalf* dst = (nt < 4) ? qb : kb;                                          \
      const size_t base = (size_t)(nt & 3)*512 + (size_t)(r16 >> 3)*256 + (r16 & 7); \
      _Pragma("unroll")                                                         \
      for (int rr = 0; rr < 4; ++rr) {                                          \
        const int tok = tok0 + tg*16 + g*4 + rr;                                \
        dst[(size_t)(tok >> 5)*2048 + base + (tok & 31)*8] = (bhalf)ACC[rr];    \
      }                                                                         \
    } else {                                                                    \
      _Pragma("unroll")                                                         \
      for (int rr = 0; rr < 4; ++rr)                                            \
        vlds[tg][(nt - 8)*16 + r16][g*4 + rr] = (bhalf)ACC[rr];                 \
    } } while (0)

  auto vlds = (bhalf(*)[64][24])(void*)smem;
  STOREJ(0, acc0); STOREJ(1, acc1); STOREJ(2, acc2);
  STOREJ(3, acc3); STOREJ(4, acc4); STOREJ(5, acc5);
#undef STOREJ
  __syncthreads();
  if (ng == 1) {
    const int f    = lane;
    const int tokG = tok0 + tg*16;
    const int tile = tokG >> 5;
    const int s    = (tokG >> 4) & 1;
    bhalf8 v0 = *(const bhalf8*)&vlds[tg][f][0];
    bhalf8 v1 = *(const bhalf8*)&vlds[tg][f][8];
    bhalf* dstv = vtb + (size_t)tile*2048 + (size_t)(f >> 5)*1024
                      + (size_t)s*512 + (size_t)(f & 31)*8;
    *(bhalf8*)dstv         = v0;
    *(bhalf8*)(dstv + 256) = v1;
  }
}

// ---------------------------------------------------------------------------
// Flash attention v7: R9's 2-q-tile structure + DOUBLE-BUFFERED K/V (P/Q reg
// sets, 2x-unrolled loop). attn is grid-limited to 2 waves/SIMD at ~170 VGPR,
// so the +64 VGPR is free; loads for it+1 issue at the TOP of each body (no
// WAR stall on the single buffer), giving a full body of latency cover.
__device__ __forceinline__ unsigned cvtpk(float lo, float hi_) {
  unsigned r;
  asm("v_cvt_pk_bf16_f32 %0, %1, %2" : "=v"(r) : "v"(lo), "v"(hi_));
  return r;
}
__device__ __forceinline__ bhalf8 mk8(unsigned a, unsigned b, unsigned c, unsigned d) {
  u32x4 u; u[0]=a; u[1]=b; u[2]=c; u[3]=d;
  return __builtin_bit_cast(bhalf8, u);
}

__global__ __launch_bounds__(256) void attn(const bhalf* __restrict__ qb,
    const bhalf* __restrict__ kb, const bhalf* __restrict__ vtb,
    float* __restrict__ out) {
  __shared__ float po[NSPLIT][64][33];
  __shared__ float pl[NSPLIT][32];

  const int lane = threadIdx.x & 63;
  const int wv   = threadIdx.x >> 6;
  const int l31  = lane & 31;
  const int hi   = lane >> 5;

  const int pr    = (blockIdx.x & 7)*64 + (blockIdx.x >> 3);
  const int qtA   = pr*2;
  const int qtB   = qtA + 1;
  const int b     = qtA >> 6;
  const int tile0 = b*64 + wv*16;
  const int fo    = hi*256 + l31*8;

  const bhalf* qpA = qb + (size_t)qtA*2048 + fo;
  const bhalf8 qfA0 = *(const bhalf8*)(qpA);
  const bhalf8 qfA1 = *(const bhalf8*)(qpA + 512);
  const bhalf8 qfA2 = *(const bhalf8*)(qpA + 1024);
  const bhalf8 qfA3 = *(const bhalf8*)(qpA + 1536);
  const bhalf* qpB = qb + (size_t)qtB*2048 + fo;
  const bhalf8 qfB0 = *(const bhalf8*)(qpB);
  const bhalf8 qfB1 = *(const bhalf8*)(qpB + 512);
  const bhalf8 qfB2 = *(const bhalf8*)(qpB + 1024);
  const bhalf8 qfB3 = *(const bhalf8*)(qpB + 1536);

  const bhalf* kpk = kb  + (size_t)tile0*2048 + fo;
  const bhalf* vpk = vtb + (size_t)tile0*2048 + fo;

  f32x16 otA0, otA1, otB0, otB1;
#pragma unroll
  for (int r = 0; r < 16; ++r) { otA0[r]=0.f; otA1[r]=0.f; otB0[r]=0.f; otB1[r]=0.f; }
  float lsA = 0.f, lsB = 0.f;

  // double-buffered K/V fragment sets (P and Q)
  bhalf8 kP0,kP1,kP2,kP3, vP0,vP1,vP2,vP3;
  bhalf8 kQ0,kQ1,kQ2,kQ3, vQ0,vQ1,vQ2,vQ3;
  bhalf8 pfA0, pfA1, pfB0, pfB1;
  f32x16 s;

#define LOADKB(IT, K0,K1,K2,K3) do { const bhalf* p_ = kpk + (IT)*2048;         \
    K0 = *(const bhalf8*)(p_);          K1 = *(const bhalf8*)(p_ + 512);        \
    K2 = *(const bhalf8*)(p_ + 1024);   K3 = *(const bhalf8*)(p_ + 1536); } while (0)
#define LOADVB(IT, V0,V1,V2,V3) do { const bhalf* p_ = vpk + (IT)*2048;         \
    V0 = *(const bhalf8*)(p_);          V1 = *(const bhalf8*)(p_ + 512);        \
    V2 = *(const bhalf8*)(p_ + 1024);   V3 = *(const bhalf8*)(p_ + 1536); } while (0)
#define QK(K0,K1,K2,K3, QF0,QF1,QF2,QF3) do {                                   \
    _Pragma("unroll") for (int r_ = 0; r_ < 16; ++r_) s[r_] = 0.f;              \
    __builtin_amdgcn_s_setprio(1);                                              \
    s = __builtin_amdgcn_mfma_f32_32x32x16_bf16(K0, QF0, s, 0, 0, 0);           \
    s = __builtin_amdgcn_mfma_f32_32x32x16_bf16(K1, QF1, s, 0, 0, 0);           \
    s = __builtin_amdgcn_mfma_f32_32x32x16_bf16(K2, QF2, s, 0, 0, 0);           \
    s = __builtin_amdgcn_mfma_f32_32x32x16_bf16(K3, QF3, s, 0, 0, 0);           \
    __builtin_amdgcn_s_setprio(0); } while (0)
#define SM(PF0, PF1, LS) do {                                                   \
    _Pragma("unroll") for (int r_ = 0; r_ < 16; ++r_)                           \
      s[r_] = __builtin_amdgcn_exp2f(s[r_]);                                    \
    LS += ((s[0]+s[1])+(s[2]+s[3])) + ((s[4]+s[5])+(s[6]+s[7]))                 \
        + ((s[8]+s[9])+(s[10]+s[11])) + ((s[12]+s[13])+(s[14]+s[15]));          \
    unsigned w0 = cvtpk(s[0],  s[1]),  w1 = cvtpk(s[2],  s[3]);                 \
    unsigned w2 = cvtpk(s[4],  s[5]),  w3 = cvtpk(s[6],  s[7]);                 \
    unsigned w4 = cvtpk(s[8],  s[9]),  w5 = cvtpk(s[10], s[11]);                \
    unsigned w6 = cvtpk(s[12], s[13]), w7 = cvtpk(s[14], s[15]);                \
    asm volatile("v_permlane32_swap_b32 %0, %1" : "+v"(w0), "+v"(w2));          \
    asm volatile("v_permlane32_swap_b32 %0, %1" : "+v"(w1), "+v"(w3));          \
    asm volatile("v_permlane32_swap_b32 %0, %1" : "+v"(w4), "+v"(w6));          \
    asm volatile("v_permlane32_swap_b32 %0, %1" : "+v"(w5), "+v"(w7));          \
    PF0 = mk8(w0, w1, w2, w3);                                                  \
    PF1 = mk8(w4, w5, w6, w7); } while (0)
#define PV(V0,V1,V2,V3, PF0, PF1, OT0, OT1) do {                                \
    __builtin_amdgcn_s_setprio(1);                                              \
    OT0 = __builtin_amdgcn_mfma_f32_32x32x16_bf16(V0, PF0, OT0, 0, 0, 0);       \
    OT0 = __builtin_amdgcn_mfma_f32_32x32x16_bf16(V1, PF1, OT0, 0, 0, 0);       \
    OT1 = __builtin_amdgcn_mfma_f32_32x32x16_bf16(V2, PF0, OT1, 0, 0, 0);       \
    OT1 = __builtin_amdgcn_mfma_f32_32x32x16_bf16(V3, PF1, OT1, 0, 0, 0);       \
    __builtin_amdgcn_s_setprio(0); } while (0)
#define BODY(K0,K1,K2,K3, V0,V1,V2,V3) do {                                     \
    QK(K0,K1,K2,K3, qfA0,qfA1,qfA2,qfA3);                                       \
    SM(pfA0, pfA1, lsA);                                                        \
    QK(K0,K1,K2,K3, qfB0,qfB1,qfB2,qfB3);                                       \
    PV(V0,V1,V2,V3, pfA0, pfA1, otA0, otA1);                                    \
    SM(pfB0, pfB1, lsB);                                                        \
    PV(V0,V1,V2,V3, pfB0, pfB1, otB0, otB1); } while (0)

  LOADKB(0, kP0,kP1,kP2,kP3);
  LOADVB(0, vP0,vP1,vP2,vP3);

  for (int it = 0; it < KVPER/32; it += 2) {
    // prefetch it+1 into Q-buffers, then compute it from P-buffers
    LOADKB(it + 1, kQ0,kQ1,kQ2,kQ3);
    LOADVB(it + 1, vQ0,vQ1,vQ2,vQ3);
    BODY(kP0,kP1,kP2,kP3, vP0,vP1,vP2,vP3);
    // prefetch it+2 into P-buffers, compute it+1 from Q-buffers
    if (it + 2 < KVPER/32) {
      LOADKB(it + 2, kP0,kP1,kP2,kP3);
      LOADVB(it + 2, vP0,vP1,vP2,vP3);
    }
    BODY(kQ0,kQ1,kQ2,kQ3, vQ0,vQ1,vQ2,vQ3);
  }

#undef LOADKB
#undef LOADVB
#undef QK
#undef SM
#undef PV
#undef BODY

  lsA += __shfl_xor(lsA, 32);
  lsB += __shfl_xor(lsB, 32);

  // ---- combine tile A, then tile B (po/pl reused) ----
#pragma unroll
  for (int r = 0; r < 16; ++r) {
    int d0 = (r & 3) + 8*(r >> 2) + 4*hi;
    po[wv][d0][l31]      = otA0[r];
    po[wv][32 + d0][l31] = otA1[r];
  }
  if (hi == 0) pl[wv][l31] = lsA;
  __syncthreads();
  {
    int q  = threadIdx.x >> 3;
    int dg = (threadIdx.x & 7) * 8;
    float L   = pl[0][q] + pl[1][q] + pl[2][q] + pl[3][q];
    float inv = 1.0f / L;
    float* orow = out + (size_t)(qtA*32 + q)*DOUT + dg;
#pragma unroll
    for (int j = 0; j < 8; ++j)
      orow[j] = (po[0][dg+j][q] + po[1][dg+j][q]
               + po[2][dg+j][q] + po[3][dg+j][q]) * inv;
  }
  __syncthreads();
#pragma unroll
  for (int r = 0; r < 16; ++r) {
    int d0 = (r & 3) + 8*(r >> 2) + 4*hi;
    po[wv][d0][l31]      = otB0[r];
    po[wv][32 + d0][l31] = otB1[r];
  }
  if (hi == 0) pl[wv][l31] = lsB;
  __syncthreads();
  {
    int q  = threadIdx.x >> 3;
    int dg = (threadIdx.x & 7) * 8;
    float L   = pl[0][q] + pl[1][q] + pl[2][q] + pl[3][q];
    float inv = 1.0f / L;
    float* orow = out + (size_t)(qtB*32 + q)*DOUT + dg;
#pragma unroll
    for (int j = 0; j < 8; ++j)
      orow[j] = (po[0][dg+j][q] + po[1][dg+j][q]
               + po[2][dg+j][q] + po[3][dg+j][q]) * inv;
  }
}

// ---------------------------------------------------------------------------
extern "C" void kernel_launch(void* const* d_in, const int* in_sizes, int n_in,
                              void* d_out, int out_size, void* d_ws, size_t ws_size,
                              hipStream_t stream) {
  const float* x  = (const float*)d_in[0];
  const float* wk = (const float*)d_in[1];
  float* out = (float*)d_out;

  char* ws = (char*)d_ws;
  bhalf* wt = (bhalf*)(ws);
  bhalf* qq = (bhalf*)(ws + Q_OFF);
  bhalf* kk = (bhalf*)(ws + K_OFF);
  bhalf* vt = (bhalf*)(ws + VT_OFF);

  prep_w  <<<dim3(384), dim3(256), 0, stream>>>(wk, wt);
  proj_qkv<<<dim3(512), dim3(512), 0, stream>>>(x, wt, qq, kk, vt);
  attn    <<<dim3(512), dim3(256), 0, stream>>>(qq, kk, vt, out);
}

// Round 17
// 49.674 us; speedup vs baseline: 1.1039x; 1.1039x over previous
//
#include <hip/hip_runtime.h>
#include <hip/hip_bf16.h>

typedef __bf16 bhalf;
typedef __attribute__((ext_vector_type(8)))  __bf16 bhalf8;
typedef __attribute__((ext_vector_type(4)))  float  f32x4;
typedef __attribute__((ext_vector_type(16))) float  f32x16;
typedef __attribute__((ext_vector_type(4)))  unsigned int u32x4;

#define NB   16
#define SEQ  2048
#define DIN  512
#define DOUT 64
#define NTOK (NB*SEQ)
#define NSPLIT 4
#define KVPER (SEQ/NSPLIT)     // 512 kv per split

// ws layout (Q/K/V fragment-packed per 32-token tile, 4 KB/tile — see R8)
#define WT_BYTES (192*512*2)
#define Q_OFF    ((size_t)WT_BYTES)
#define QKV_BYTES ((size_t)NTOK*DOUT*2)
#define K_OFF    (Q_OFF + QKV_BYTES)
#define VT_OFF   (K_OFF + QKV_BYTES)

__device__ __forceinline__ void gl_lds16(const void* g, void* l) {
  __builtin_amdgcn_global_load_lds(
      (const __attribute__((address_space(1))) void*)g,
      (__attribute__((address_space(3))) void*)l, 16, 0, 0);
}

// ---------------------------------------------------------------------------
__global__ __launch_bounds__(256) void prep_w(const float* __restrict__ wk,
                                              bhalf* __restrict__ wt) {
  int tid  = blockIdx.x*256 + threadIdx.x;
  int slot = tid >> 15;
  int rem  = tid & 32767;
  int k    = rem >> 6;
  int col  = rem & 63;
  float v  = wk[tid];
  if (slot == 0) v *= 0.18033688011112042f;    // (1/8)*log2(e)
  wt[(size_t)(slot*64 + col)*DIN + k] = (bhalf)v;
}

// ---------------------------------------------------------------------------
// QKV projection v6 (R9 verbatim — best measured): 512 threads = 8 waves =
// (4 token-groups) x (2 n-groups); dual-operand LDS staging via
// global_load_lds; fragment-packed outputs.
__global__ __launch_bounds__(512) void proj_qkv(const float* __restrict__ x,
    const bhalf* __restrict__ wt, bhalf* __restrict__ qb,
    bhalf* __restrict__ kb, bhalf* __restrict__ vtb) {
  __shared__ __align__(16) char smem[81920];   // xs[2][16KB] + ws[2][24KB]
  char* const xs  = smem;
  char* const wsl = smem + 32768;

  const int tid  = threadIdx.x;
  const int lane = tid & 63;
  const int wv   = tid >> 6;       // 0..7
  const int tg   = wv & 3;         // token group (16 tokens)
  const int ng   = wv >> 2;        // n group: nt 0..5 / 6..11
  const int r16  = lane & 15;
  const int g    = lane >> 4;
  const int tok0 = blockIdx.x * 64;

  const char* const xg = (const char*)(x + (size_t)tok0 * DIN);
  const char* const wg = (const char*)wt;

  auto stage = [&](int buf, int c) {
#pragma unroll
    for (int i = 0; i < 5; ++i) {
      const int p = wv*5 + i;
      if (p < 24) {
        const int n = p*8 + (lane >> 3);
        const int s = lane & 7;
        gl_lds16(wg + (size_t)n*1024 + c*128 + ((s ^ (n & 7)) << 4),
                 wsl + buf*24576 + p*1024);
      } else {
        const int q = p - 24;
        const int r = q*4 + (lane >> 4);
        const int s = lane & 15;
        gl_lds16(xg + (size_t)r*2048 + c*256 + ((s ^ (r & 7)) << 4),
                 xs + buf*16384 + q*1024);
      }
    }
  };

  f32x4 acc0 = {0.f,0.f,0.f,0.f}, acc1 = acc0, acc2 = acc0,
        acc3 = acc0, acc4 = acc0, acc5 = acc0;

  stage(0, 0);
  __syncthreads();

  const int row = tg*16 + r16;
  const int rx7 = r16 & 7;

  int buf = 0;
  for (int c = 0; c < 8; ++c) {
    if (c < 7) stage(buf ^ 1, c + 1);
    const char* xrow = xs  + buf*16384 + row*256;
    const char* wb   = wsl + buf*24576;
#pragma unroll
    for (int kk = 0; kk < 2; ++kk) {
      const int sa = kk*8 + g*2;
      f32x4 xa = *(const f32x4*)(xrow + (( sa      ^ rx7) << 4));
      f32x4 xc = *(const f32x4*)(xrow + (((sa + 1) ^ rx7) << 4));
      bhalf8 a;
      a[0]=(bhalf)xa[0]; a[1]=(bhalf)xa[1]; a[2]=(bhalf)xa[2]; a[3]=(bhalf)xa[3];
      a[4]=(bhalf)xc[0]; a[5]=(bhalf)xc[1]; a[6]=(bhalf)xc[2]; a[7]=(bhalf)xc[3];
      const int sb = (kk*4 + g) ^ rx7;
      __builtin_amdgcn_s_setprio(1);
#define MF(J, ACC) do {                                                         \
        const int nt_ = ng*6 + (J);                                             \
        const bhalf8 bf_ = *(const bhalf8*)(wb + (nt_*16 + r16)*128 + (sb << 4)); \
        ACC = __builtin_amdgcn_mfma_f32_16x16x32_bf16(a, bf_, ACC, 0, 0, 0);    \
      } while (0)
      MF(0, acc0); MF(1, acc1); MF(2, acc2);
      MF(3, acc3); MF(4, acc4); MF(5, acc5);
#undef MF
      __builtin_amdgcn_s_setprio(0);
    }
    __syncthreads();
    buf ^= 1;
  }

#define STOREJ(J, ACC) do {                                                     \
    const int nt = ng*6 + (J);                                                  \
    if (nt < 8) {                                                               \
      bhalf* dst = (nt < 4) ? qb : kb;                                          \
      const size_t base = (size_t)(nt & 3)*512 + (size_t)(r16 >> 3)*256 + (r16 & 7); \
      _Pragma("unroll")                                                         \
      for (int rr = 0; rr < 4; ++rr) {                                          \
        const int tok = tok0 + tg*16 + g*4 + rr;                                \
        dst[(size_t)(tok >> 5)*2048 + base + (tok & 31)*8] = (bhalf)ACC[rr];    \
      }                                                                         \
    } else {                                                                    \
      _Pragma("unroll")                                                         \
      for (int rr = 0; rr < 4; ++rr)                                            \
        vlds[tg][(nt - 8)*16 + r16][g*4 + rr] = (bhalf)ACC[rr];                 \
    } } while (0)

  auto vlds = (bhalf(*)[64][24])(void*)smem;
  STOREJ(0, acc0); STOREJ(1, acc1); STOREJ(2, acc2);
  STOREJ(3, acc3); STOREJ(4, acc4); STOREJ(5, acc5);
#undef STOREJ
  __syncthreads();
  if (ng == 1) {
    const int f    = lane;
    const int tokG = tok0 + tg*16;
    const int tile = tokG >> 5;
    const int s    = (tokG >> 4) & 1;
    bhalf8 v0 = *(const bhalf8*)&vlds[tg][f][0];
    bhalf8 v1 = *(const bhalf8*)&vlds[tg][f][8];
    bhalf* dstv = vtb + (size_t)tile*2048 + (size_t)(f >> 5)*1024
                      + (size_t)s*512 + (size_t)(f & 31)*8;
    *(bhalf8*)dstv         = v0;
    *(bhalf8*)(dstv + 256) = v1;
  }
}

// ---------------------------------------------------------------------------
// Flash attention (R9 version verbatim — best measured): 2 q-tiles per wave
// share one K/V stream; QK_A SM_A QK_B PV_A SM_B PV_B interleave; fragment-
// packed loads; fixed-reference softmax; kv-split x4 with LDS combine.
__device__ __forceinline__ unsigned cvtpk(float lo, float hi_) {
  unsigned r;
  asm("v_cvt_pk_bf16_f32 %0, %1, %2" : "=v"(r) : "v"(lo), "v"(hi_));
  return r;
}
__device__ __forceinline__ bhalf8 mk8(unsigned a, unsigned b, unsigned c, unsigned d) {
  u32x4 u; u[0]=a; u[1]=b; u[2]=c; u[3]=d;
  return __builtin_bit_cast(bhalf8, u);
}

__global__ __launch_bounds__(256) void attn(const bhalf* __restrict__ qb,
    const bhalf* __restrict__ kb, const bhalf* __restrict__ vtb,
    float* __restrict__ out) {
  __shared__ float po[NSPLIT][64][33];
  __shared__ float pl[NSPLIT][32];

  const int lane = threadIdx.x & 63;
  const int wv   = threadIdx.x >> 6;
  const int l31  = lane & 31;
  const int hi   = lane >> 5;

  const int pr    = (blockIdx.x & 7)*64 + (blockIdx.x >> 3);
  const int qtA   = pr*2;
  const int qtB   = qtA + 1;
  const int b     = qtA >> 6;
  const int tile0 = b*64 + wv*16;
  const int fo    = hi*256 + l31*8;

  const bhalf* qpA = qb + (size_t)qtA*2048 + fo;
  const bhalf8 qfA0 = *(const bhalf8*)(qpA);
  const bhalf8 qfA1 = *(const bhalf8*)(qpA + 512);
  const bhalf8 qfA2 = *(const bhalf8*)(qpA + 1024);
  const bhalf8 qfA3 = *(const bhalf8*)(qpA + 1536);
  const bhalf* qpB = qb + (size_t)qtB*2048 + fo;
  const bhalf8 qfB0 = *(const bhalf8*)(qpB);
  const bhalf8 qfB1 = *(const bhalf8*)(qpB + 512);
  const bhalf8 qfB2 = *(const bhalf8*)(qpB + 1024);
  const bhalf8 qfB3 = *(const bhalf8*)(qpB + 1536);

  const bhalf* kpk = kb  + (size_t)tile0*2048 + fo;
  const bhalf* vpk = vtb + (size_t)tile0*2048 + fo;

  f32x16 otA0, otA1, otB0, otB1;
#pragma unroll
  for (int r = 0; r < 16; ++r) { otA0[r]=0.f; otA1[r]=0.f; otB0[r]=0.f; otB1[r]=0.f; }
  float lsA = 0.f, lsB = 0.f;

  bhalf8 kf0, kf1, kf2, kf3;
  bhalf8 vf0, vf1, vf2, vf3;
  bhalf8 pfA0, pfA1, pfB0, pfB1;
  f32x16 s;

#define LOADK(IT) do { const bhalf* p_ = kpk + (IT)*2048;                       \
    kf0 = *(const bhalf8*)(p_);          kf1 = *(const bhalf8*)(p_ + 512);      \
    kf2 = *(const bhalf8*)(p_ + 1024);   kf3 = *(const bhalf8*)(p_ + 1536); } while (0)
#define LOADV(IT) do { const bhalf* p_ = vpk + (IT)*2048;                       \
    vf0 = *(const bhalf8*)(p_);          vf1 = *(const bhalf8*)(p_ + 512);      \
    vf2 = *(const bhalf8*)(p_ + 1024);   vf3 = *(const bhalf8*)(p_ + 1536); } while (0)
#define QK(QF0, QF1, QF2, QF3) do {                                             \
    _Pragma("unroll") for (int r_ = 0; r_ < 16; ++r_) s[r_] = 0.f;              \
    __builtin_amdgcn_s_setprio(1);                                              \
    s = __builtin_amdgcn_mfma_f32_32x32x16_bf16(kf0, QF0, s, 0, 0, 0);          \
    s = __builtin_amdgcn_mfma_f32_32x32x16_bf16(kf1, QF1, s, 0, 0, 0);          \
    s = __builtin_amdgcn_mfma_f32_32x32x16_bf16(kf2, QF2, s, 0, 0, 0);          \
    s = __builtin_amdgcn_mfma_f32_32x32x16_bf16(kf3, QF3, s, 0, 0, 0);          \
    __builtin_amdgcn_s_setprio(0); } while (0)
#define SM(PF0, PF1, LS) do {                                                   \
    _Pragma("unroll") for (int r_ = 0; r_ < 16; ++r_)                           \
      s[r_] = __builtin_amdgcn_exp2f(s[r_]);                                    \
    LS += ((s[0]+s[1])+(s[2]+s[3])) + ((s[4]+s[5])+(s[6]+s[7]))                 \
        + ((s[8]+s[9])+(s[10]+s[11])) + ((s[12]+s[13])+(s[14]+s[15]));          \
    unsigned w0 = cvtpk(s[0],  s[1]),  w1 = cvtpk(s[2],  s[3]);                 \
    unsigned w2 = cvtpk(s[4],  s[5]),  w3 = cvtpk(s[6],  s[7]);                 \
    unsigned w4 = cvtpk(s[8],  s[9]),  w5 = cvtpk(s[10], s[11]);                \
    unsigned w6 = cvtpk(s[12], s[13]), w7 = cvtpk(s[14], s[15]);                \
    asm volatile("v_permlane32_swap_b32 %0, %1" : "+v"(w0), "+v"(w2));          \
    asm volatile("v_permlane32_swap_b32 %0, %1" : "+v"(w1), "+v"(w3));          \
    asm volatile("v_permlane32_swap_b32 %0, %1" : "+v"(w4), "+v"(w6));          \
    asm volatile("v_permlane32_swap_b32 %0, %1" : "+v"(w5), "+v"(w7));          \
    PF0 = mk8(w0, w1, w2, w3);                                                  \
    PF1 = mk8(w4, w5, w6, w7); } while (0)
#define PV(PF0, PF1, OT0, OT1) do {                                             \
    __builtin_amdgcn_s_setprio(1);                                              \
    OT0 = __builtin_amdgcn_mfma_f32_32x32x16_bf16(vf0, PF0, OT0, 0, 0, 0);      \
    OT0 = __builtin_amdgcn_mfma_f32_32x32x16_bf16(vf1, PF1, OT0, 0, 0, 0);      \
    OT1 = __builtin_amdgcn_mfma_f32_32x32x16_bf16(vf2, PF0, OT1, 0, 0, 0);      \
    OT1 = __builtin_amdgcn_mfma_f32_32x32x16_bf16(vf3, PF1, OT1, 0, 0, 0);      \
    __builtin_amdgcn_s_setprio(0); } while (0)

  LOADK(0);
  LOADV(0);

  for (int it = 0; it < KVPER/32; ++it) {
    QK(qfA0, qfA1, qfA2, qfA3);
    SM(pfA0, pfA1, lsA);
    QK(qfB0, qfB1, qfB2, qfB3);
    if (it < KVPER/32 - 1) LOADK(it + 1);
    PV(pfA0, pfA1, otA0, otA1);
    SM(pfB0, pfB1, lsB);
    PV(pfB0, pfB1, otB0, otB1);
    if (it < KVPER/32 - 1) LOADV(it + 1);
  }

#undef LOADK
#undef LOADV
#undef QK
#undef SM
#undef PV

  lsA += __shfl_xor(lsA, 32);
  lsB += __shfl_xor(lsB, 32);

  // ---- combine tile A, then tile B (po/pl reused) ----
#pragma unroll
  for (int r = 0; r < 16; ++r) {
    int d0 = (r & 3) + 8*(r >> 2) + 4*hi;
    po[wv][d0][l31]      = otA0[r];
    po[wv][32 + d0][l31] = otA1[r];
  }
  if (hi == 0) pl[wv][l31] = lsA;
  __syncthreads();
  {
    int q  = threadIdx.x >> 3;
    int dg = (threadIdx.x & 7) * 8;
    float L   = pl[0][q] + pl[1][q] + pl[2][q] + pl[3][q];
    float inv = 1.0f / L;
    float* orow = out + (size_t)(qtA*32 + q)*DOUT + dg;
#pragma unroll
    for (int j = 0; j < 8; ++j)
      orow[j] = (po[0][dg+j][q] + po[1][dg+j][q]
               + po[2][dg+j][q] + po[3][dg+j][q]) * inv;
  }
  __syncthreads();
#pragma unroll
  for (int r = 0; r < 16; ++r) {
    int d0 = (r & 3) + 8*(r >> 2) + 4*hi;
    po[wv][d0][l31]      = otB0[r];
    po[wv][32 + d0][l31] = otB1[r];
  }
  if (hi == 0) pl[wv][l31] = lsB;
  __syncthreads();
  {
    int q  = threadIdx.x >> 3;
    int dg = (threadIdx.x & 7) * 8;
    float L   = pl[0][q] + pl[1][q] + pl[2][q] + pl[3][q];
    float inv = 1.0f / L;
    float* orow = out + (size_t)(qtB*32 + q)*DOUT + dg;
#pragma unroll
    for (int j = 0; j < 8; ++j)
      orow[j] = (po[0][dg+j][q] + po[1][dg+j][q]
               + po[2][dg+j][q] + po[3][dg+j][q]) * inv;
  }
}

// ---------------------------------------------------------------------------
extern "C" void kernel_launch(void* const* d_in, const int* in_sizes, int n_in,
                              void* d_out, int out_size, void* d_ws, size_t ws_size,
                              hipStream_t stream) {
  const float* x  = (const float*)d_in[0];
  const float* wk = (const float*)d_in[1];
  float* out = (float*)d_out;

  char* ws = (char*)d_ws;
  bhalf* wt = (bhalf*)(ws);
  bhalf* qq = (bhalf*)(ws + Q_OFF);
  bhalf* kk = (bhalf*)(ws + K_OFF);
  bhalf* vt = (bhalf*)(ws + VT_OFF);

  prep_w  <<<dim3(384), dim3(256), 0, stream>>>(wk, wt);
  proj_qkv<<<dim3(512), dim3(512), 0, stream>>>(x, wt, qq, kk, vt);
  attn    <<<dim3(512), dim3(256), 0, stream>>>(qq, kk, vt, out);
}